// Round 1
// baseline (86.735 us; speedup 1.0000x reference)
//
#include <hip/hip_runtime.h>
#include <math.h>

#define V      32000
#define N      2048
#define NQ     (V / 4)      // 8000 float4 per row
#define TPB    512
#define NWAVES (TPB / 64)
#define EPSU   1e-5f

// ---------------- kernel 1: init fo table + accumulators ----------------
__global__ void init_kernel(int* __restrict__ fo, float* __restrict__ sums,
                            int* __restrict__ cnt) {
    int idx = blockIdx.x * blockDim.x + threadIdx.x;
    if (idx < V) fo[idx] = 0x7FFFFFFF;
    if (idx == 0) { sums[0] = 0.f; sums[1] = 0.f; *cnt = 0; }
}

// ---------------- kernel 2: build first-occurrence + count ----------------
__global__ void fo_kernel(const int* __restrict__ t, int* __restrict__ fo,
                          int* __restrict__ cnt) {
    int i = blockIdx.x * blockDim.x + threadIdx.x;
    if (i < N) {
        int ti = t[i];
        atomicMin(&fo[ti], i);
        if (ti != 0) atomicAdd(cnt, 1);
    }
}

// ---------------- kernel 3: per-row fused lse + UL gather + CE ----------------
__global__ __launch_bounds__(TPB) void
row_kernel(const float* __restrict__ x, const int* __restrict__ t,
           const int* __restrict__ fo, float* __restrict__ sums) {
    const int i  = blockIdx.x;
    const int ti = t[i];
    if (ti == 0) return;   // ignored row: no CE, no UL

    __shared__ float list[2048];          // compacted candidate logits
    __shared__ int   count;
    __shared__ float xt_sh;               // x[i, t[i]]
    __shared__ float red_m[NWAVES], red_s[NWAVES], acc_sh[NWAVES];
    __shared__ float lse_sh;

    if (threadIdx.x == 0) count = 0;
    __syncthreads();

    const float4* row4 = (const float4*)(x + (size_t)i * V);
    const int4*   fo4  = (const int4*)fo;

    float m = -INFINITY, s = 0.f;
    for (int q = threadIdx.x; q < NQ; q += TPB) {
        float4 xv = row4[q];
        int4   f  = fo4[q];
        // online softmax update (4 elems)
        float lm = fmaxf(fmaxf(xv.x, xv.y), fmaxf(xv.z, xv.w));
        float nm = fmaxf(m, lm);
        s = s * __expf(m - nm)
          + __expf(xv.x - nm) + __expf(xv.y - nm)
          + __expf(xv.z - nm) + __expf(xv.w - nm);
        m = nm;
        // candidate compaction: v appeared strictly before row i, v != t[i], v != 0
        int vb = q << 2;
        if ((f.x < i) && (vb     != ti) && (vb != 0)) { int p = atomicAdd(&count, 1); list[p] = xv.x; }
        if ((f.y < i) && (vb + 1 != ti))              { int p = atomicAdd(&count, 1); list[p] = xv.y; }
        if ((f.z < i) && (vb + 2 != ti))              { int p = atomicAdd(&count, 1); list[p] = xv.z; }
        if ((f.w < i) && (vb + 3 != ti))              { int p = atomicAdd(&count, 1); list[p] = xv.w; }
        // capture x[i, t[i]] for CE
        if (vb     == ti) xt_sh = xv.x;
        if (vb + 1 == ti) xt_sh = xv.y;
        if (vb + 2 == ti) xt_sh = xv.z;
        if (vb + 3 == ti) xt_sh = xv.w;
    }

    // wave-level (m,s) butterfly reduce
    #pragma unroll
    for (int off = 32; off > 0; off >>= 1) {
        float mo = __shfl_xor(m, off, 64);
        float so = __shfl_xor(s, off, 64);
        float nm = fmaxf(m, mo);
        s = s * __expf(m - nm) + so * __expf(mo - nm);
        m = nm;
    }
    const int wave = threadIdx.x >> 6;
    const int lane = threadIdx.x & 63;
    if (lane == 0) { red_m[wave] = m; red_s[wave] = s; }
    __syncthreads();
    if (threadIdx.x == 0) {
        float M = red_m[0], S = red_s[0];
        #pragma unroll
        for (int w = 1; w < NWAVES; ++w) {
            float mo = red_m[w], so = red_s[w];
            float nm = fmaxf(M, mo);
            S = S * __expf(M - nm) + so * __expf(mo - nm);
            M = nm;
        }
        lse_sh = M + __logf(S);
    }
    __syncthreads();

    const float lse = lse_sh;
    const int   nc  = count;

    // UL over compacted candidates
    float acc = 0.f;
    for (int k = threadIdx.x; k < nc; k += TPB) {
        float p = __expf(list[k] - lse);
        acc += __logf(fmaxf(1.f - p, EPSU));
    }
    #pragma unroll
    for (int off = 32; off > 0; off >>= 1)
        acc += __shfl_xor(acc, off, 64);
    if (lane == 0) acc_sh[wave] = acc;
    __syncthreads();
    if (threadIdx.x == 0) {
        float tot = 0.f;
        #pragma unroll
        for (int w = 0; w < NWAVES; ++w) tot += acc_sh[w];
        atomicAdd(&sums[0], -tot);          // ul partial
        atomicAdd(&sums[1], lse - xt_sh);   // nll partial
    }
}

// ---------------- kernel 4: finalize ----------------
__global__ void final_kernel(const float* __restrict__ sums,
                             const int* __restrict__ cnt,
                             float* __restrict__ out) {
    float c = (float)(*cnt);
    out[0] = (1.0f * sums[0] + sums[1]) / c;   // ALPHA = 1
}

extern "C" void kernel_launch(void* const* d_in, const int* in_sizes, int n_in,
                              void* d_out, int out_size, void* d_ws, size_t ws_size,
                              hipStream_t stream) {
    const float* x = (const float*)d_in[0];
    const int*   t = (const int*)d_in[1];
    float* out = (float*)d_out;

    int*   fo   = (int*)d_ws;
    float* sums = (float*)((char*)d_ws + (size_t)V * sizeof(int));
    int*   cnt  = (int*)((char*)d_ws + (size_t)V * sizeof(int) + 2 * sizeof(float));

    hipLaunchKernelGGL(init_kernel, dim3((V + 255) / 256), dim3(256), 0, stream, fo, sums, cnt);
    hipLaunchKernelGGL(fo_kernel,   dim3((N + 255) / 256), dim3(256), 0, stream, t, fo, cnt);
    hipLaunchKernelGGL(row_kernel,  dim3(N), dim3(TPB), 0, stream, x, t, fo, sums);
    hipLaunchKernelGGL(final_kernel, dim3(1), dim3(1), 0, stream, sums, cnt, out);
}